// Round 6
// baseline (46.055 us; speedup 1.0000x reference)
//
#include <hip/hip_runtime.h>

// Exact decision boundary for  RN_f32(inter/uni) > (float)0.7 :
//   c = 0.7f = 0x3f333333, succ(c) = 0x3f333334 (even mantissa).
//   RN(x) > c  <=>  x >= M  where M = (c + succ(c))/2 (tie rounds to even
//   = succ(c) > c, so ">=" is correct).  M = 23488103 * 2^-25 (25 sig bits),
//   uni has <=24 sig bits  =>  M*(double)uni is EXACT, comparison is exact.
//   uni >= 2 always here (every box area >= 1), so uni==0 never occurs.
#define M_BOUND 0.7000000178813934326171875

__device__ __forceinline__ unsigned long long make_key(unsigned int sbits,
                                                       unsigned int idx) {
    // descending score, ascending index tie-break (stable argsort(-score))
    return (((unsigned long long)(~sbits)) << 32) | idx;
}

// ---------------------------------------------------------------------------
// Kernel A: partial rank counts, 2 i-keys per thread, NO LDS.
// The y-tile key index (ybase+kk) is wave-uniform -> compiler scalarizes the
// score load to s_load (scalar cache) and builds the key in an SGPR pair;
// v_cmp_lt_u64 takes the sgpr-pair as src0.  Inner loop = pure VALU+SALU.
// grid = (N/512, N/256) = 512 blocks -> 2 blocks/CU.
// ---------------------------------------------------------------------------
__global__ __launch_bounds__(256)
void nms_rank_partial(const float* __restrict__ score,
                      unsigned int* __restrict__ partial, int N)
{
    const int tid   = threadIdx.x;
    const int y     = blockIdx.y;
    const int ybase = y * 256;

    const int i0 = blockIdx.x * 512 + tid;
    const unsigned long long k0 = make_key(__float_as_uint(score[i0      ]), i0      );
    const unsigned long long k1 = make_key(__float_as_uint(score[i0 + 256]), i0 + 256);

    unsigned int c0 = 0, c1 = 0;
    #pragma unroll 16
    for (int kk = 0; kk < 256; ++kk) {
        const int t = ybase + kk;                       // uniform
        const unsigned long long ok =
            make_key(__float_as_uint(score[t]), (unsigned int)t);  // sgpr pair
        c0 += (ok < k0) ? 1u : 0u;
        c1 += (ok < k1) ? 1u : 0u;
    }
    unsigned int* row = partial + (size_t)y * N;
    row[i0      ] = c0;
    row[i0 + 256] = c1;
}

// ---------------------------------------------------------------------------
// Kernel B: reduce partial ranks (32 independent coalesced loads), scatter
// box + area to sorted slot, zero the suppression mask.
// ---------------------------------------------------------------------------
__global__ __launch_bounds__(256)
void nms_scatter(const float4* __restrict__ bbox,
                 const unsigned int* __restrict__ partial,
                 float4* __restrict__ sortedBox,
                 float* __restrict__ sortedArea,
                 unsigned int* __restrict__ mask, int N)
{
    const int i = blockIdx.x * 256 + threadIdx.x;
    const int ny = N / 256;
    unsigned int r = 0;
    #pragma unroll 8
    for (int y = 0; y < ny; ++y)
        r += partial[(size_t)y * N + i];
    const float4 b = bbox[i];
    sortedBox[r]  = b;
    sortedArea[r] = (b.z - b.x) * (b.w - b.y);   // (y2-y1)*(x2-x1), once (as np)
    mask[i] = 0u;
}

// ---------------------------------------------------------------------------
// Kernel C: suppressed[j] |= any i<j with IoU > 0.7.  Branchless body; the
// f64 boundary compare's mask is accumulated with __ballot into a UNIFORM
// u64 (sgpr) via s_or_b64 -- the accumulate leaves the VALU.  Block-level
// uniform split: 496 off-diag blocks run without the i<j predicate; 32 diag
// blocks keep it.  4 waves split the i-tile (64 k's each); each lane owns
// 4 j's fed by one LDS broadcast.
// ---------------------------------------------------------------------------
__global__ __launch_bounds__(256)
void nms_suppress(const float4* __restrict__ sortedBox,
                  const float* __restrict__ sortedArea,
                  unsigned int* __restrict__ mask)
{
    // decode triangular index: x = bj*(bj+1)/2 + bi, bi <= bj
    const int x = blockIdx.x;
    int bj = (int)((sqrtf(8.0f * (float)x + 1.0f) - 1.0f) * 0.5f);
    while ((bj + 1) * (bj + 2) / 2 <= x) ++bj;
    while (bj * (bj + 1) / 2 > x) --bj;
    const int bi = x - bj * (bj + 1) / 2;

    __shared__ float4 tile[256];
    __shared__ float  tarea[256];
    const int tid = threadIdx.x;

    tile[tid]  = sortedBox[bi * 256 + tid];
    tarea[tid] = sortedArea[bi * 256 + tid];
    __syncthreads();

    const int w = tid >> 6;           // wave id: k-quarter of the i-tile
    const int l = tid & 63;

    float4 jb[4];
    float  aj[4];
    #pragma unroll
    for (int m = 0; m < 4; ++m) {
        const int j = bj * 256 + m * 64 + l;
        jb[m] = sortedBox[j];
        aj[m] = sortedArea[j];
    }

    unsigned long long sup[4] = {0ull, 0ull, 0ull, 0ull};
    const int kbase = w * 64;

    if (bi < bj) {                    // uniform branch: no predicate needed
        #pragma unroll 2
        for (int k = 0; k < 64; ++k) {
            const float4 bo = tile[kbase + k];
            const float  ai = tarea[kbase + k];
            #pragma unroll
            for (int m = 0; m < 4; ++m) {
                const float iy1 = fmaxf(bo.x, jb[m].x);
                const float ix1 = fmaxf(bo.y, jb[m].y);
                const float iy2 = fminf(bo.z, jb[m].z);
                const float ix2 = fminf(bo.w, jb[m].w);
                const float ih  = fmaxf(iy2 - iy1, 0.0f);
                const float iw  = fmaxf(ix2 - ix1, 0.0f);
                float inter = ih * iw;
                asm volatile("" : "+v"(inter));   // block (s - ih*iw) -> fma
                const float s   = ai + aj[m];
                const float uni = s - inter;
                sup[m] |= __ballot((double)inter >= M_BOUND * (double)uni);
            }
        }
    } else {                          // diagonal: predicate i<j per pair
        #pragma unroll 2
        for (int k = 0; k < 64; ++k) {
            const float4 bo = tile[kbase + k];
            const float  ai = tarea[kbase + k];
            const int    ig = kbase + k;
            #pragma unroll
            for (int m = 0; m < 4; ++m) {
                const float iy1 = fmaxf(bo.x, jb[m].x);
                const float ix1 = fmaxf(bo.y, jb[m].y);
                const float iy2 = fminf(bo.z, jb[m].z);
                const float ix2 = fminf(bo.w, jb[m].w);
                const float ih  = fmaxf(iy2 - iy1, 0.0f);
                const float iw  = fmaxf(ix2 - ix1, 0.0f);
                float inter = ih * iw;
                asm volatile("" : "+v"(inter));
                const float s   = ai + aj[m];
                const float uni = s - inter;
                const bool hit  = ((double)inter >= M_BOUND * (double)uni)
                                  && (ig < m * 64 + l);
                sup[m] |= __ballot(hit);
            }
        }
    }

    #pragma unroll
    for (int m = 0; m < 4; ++m)
        if ((sup[m] >> l) & 1ull)
            atomicOr(&mask[bj * 256 + m * 64 + l], 1u);
}

// ---------------------------------------------------------------------------
// Kernel D: keep = !suppressed; write masked sorted boxes + keep flags.
// d_out layout: [N*4 floats boxes][N floats keep].
// ---------------------------------------------------------------------------
__global__ __launch_bounds__(256)
void nms_output(const float4* __restrict__ sortedBox,
                const unsigned int* __restrict__ mask,
                float* __restrict__ out, int N)
{
    const int j = blockIdx.x * 256 + threadIdx.x;
    const float s = (mask[j] == 0u) ? 1.0f : 0.0f;
    const float4 b = sortedBox[j];
    float4 o;
    o.x = b.x * s; o.y = b.y * s; o.z = b.z * s; o.w = b.w * s;
    ((float4*)out)[j] = o;
    out[N * 4 + j] = s;
}

extern "C" void kernel_launch(void* const* d_in, const int* in_sizes, int n_in,
                              void* d_out, int out_size, void* d_ws, size_t ws_size,
                              hipStream_t stream) {
    const float* bbox  = (const float*)d_in[0];   // [1, N, 4] (y1,x1,y2,x2)
    const float* score = (const float*)d_in[1];   // [1, N]
    const int N = in_sizes[1];                    // 8192
    const int nb = N / 256;                       // 32

    char* ws = (char*)d_ws;
    float4*       sortedBox  = (float4*)ws;                               // N*16 B
    float*        sortedArea = (float*)(ws + (size_t)N * 16);             // N*4 B
    unsigned int* mask       = (unsigned int*)(ws + (size_t)N * 20);      // N*4 B
    unsigned int* partial    = (unsigned int*)(ws + (size_t)N * 24);      // nb*N*4 B

    nms_rank_partial<<<dim3(N / 512, nb), 256, 0, stream>>>(score, partial, N);
    nms_scatter<<<nb, 256, 0, stream>>>((const float4*)bbox, partial,
                                        sortedBox, sortedArea, mask, N);
    nms_suppress<<<nb * (nb + 1) / 2, 256, 0, stream>>>(sortedBox, sortedArea,
                                                        mask);
    nms_output<<<nb, 256, 0, stream>>>(sortedBox, mask, (float*)d_out, N);
}